// Round 10
// baseline (417.057 us; speedup 1.0000x reference)
//
#include <hip/hip_runtime.h>

// GAT (3 layers, heads=1) + virtual-node MLP on MI355X.
// CSR via atomic-free counting sort; projections via MFMA bf16 GEMM
// (attention dots fused as 2 extra B columns); fused online-softmax aggregate
// (exact-count chunks, rescale-on-growth-only, bf16-only node features).

constexpr int D = 64;
constexpr int BSH = 9;            // log2(nodes per bucket)
constexpr int BNODES = 1 << BSH;  // 512 nodes per bucket
constexpr int WSC = 512;          // scatter workgroups
constexpr int WCOL = 80;          // Wext padded cols (64 + s_src + s_dst + pad)

typedef __attribute__((ext_vector_type(8))) short bf16x8;
typedef __attribute__((ext_vector_type(4))) float f32x4;

__device__ __forceinline__ float lrelu(float v, float s) { return v >= 0.f ? v : v * s; }

__device__ __forceinline__ unsigned short f2bf(float f) {
  unsigned u = __float_as_uint(f);
  return (unsigned short)((u + 0x7FFFu + ((u >> 16) & 1u)) >> 16);
}
__device__ __forceinline__ float bf2f(unsigned short b) {
  return __uint_as_float((unsigned)b << 16);
}

// ---------------- f32 -> bf16 bulk convert ----------------

__global__ __launch_bounds__(256) void convert_kernel(const float* __restrict__ in,
                                                      unsigned short* __restrict__ out,
                                                      size_t n4) {
  size_t i = (size_t)blockIdx.x * blockDim.x + threadIdx.x;
  if (i >= n4) return;
  float4 v = ((const float4*)in)[i];
  ushort4 o = {f2bf(v.x), f2bf(v.y), f2bf(v.z), f2bf(v.w)};
  ((ushort4*)out)[i] = o;
}

// ---------------- Wext build: [W | W.a_src | W.a_dst | 0] as bf16 [64][80] ----------------

__global__ __launch_bounds__(64) void prep_kernel(
    const float* __restrict__ W0, const float* __restrict__ as0, const float* __restrict__ ad0,
    const float* __restrict__ W1, const float* __restrict__ as1, const float* __restrict__ ad1,
    const float* __restrict__ W2, const float* __restrict__ as2, const float* __restrict__ ad2,
    const float* __restrict__ W3, unsigned short* __restrict__ wext) {
  int b = blockIdx.x;
  int k = threadIdx.x;
  const float* W = b == 0 ? W0 : b == 1 ? W1 : b == 2 ? W2 : W3;
  const float* as = b == 0 ? as0 : b == 1 ? as1 : as2;
  const float* ad = b == 0 ? ad0 : b == 1 ? ad1 : ad2;
  unsigned short* o = wext + (size_t)b * D * WCOL + (size_t)k * WCOL;
  float ss = 0.f, sd = 0.f;
  for (int c = 0; c < D; ++c) {
    float w = W[k * D + c];
    o[c] = f2bf(w);
    if (b < 3) { ss += w * as[c]; sd += w * ad[c]; }
  }
  o[64] = (b < 3) ? f2bf(ss) : 0;
  o[65] = (b < 3) ? f2bf(sd) : 0;
  for (int c = 66; c < WCOL; ++c) o[c] = 0;
}

// ---------------- CSR build (atomic-free counting sort) ----------------

__global__ __launch_bounds__(256) void count_kernel(const int* __restrict__ ei,
                                                    int* __restrict__ cnt, int E, int N,
                                                    int B, int chunk) {
  __shared__ int hist[256];
  int w = blockIdx.x;
  int t = threadIdx.x;
  for (int b = t; b < B; b += 256) hist[b] = 0;
  __syncthreads();
  int beg = w * chunk, end = min(beg + chunk, E + N);
  for (int i = beg + t; i < end; i += 256) {
    int d = (i < E) ? ei[E + i] : (i - E);
    atomicAdd(&hist[d >> BSH], 1);
  }
  __syncthreads();
  for (int b = t; b < B; b += 256) cnt[b * WSC + w] = hist[b];
}

__global__ __launch_bounds__(256) void block_sum_kernel(const int* __restrict__ deg,
                                                        int* __restrict__ blk, int n) {
  int t = threadIdx.x;
  int i = blockIdx.x * 256 + t;
  int v = (i < n) ? deg[i] : 0;
#pragma unroll
  for (int off = 32; off; off >>= 1) v += __shfl_xor(v, off);
  __shared__ int ws[4];
  if ((t & 63) == 0) ws[t >> 6] = v;
  __syncthreads();
  if (t == 0) blk[blockIdx.x] = ws[0] + ws[1] + ws[2] + ws[3];
}

__global__ __launch_bounds__(1024) void blk_scan_kernel(int* __restrict__ blk,
                                                        int* __restrict__ blk_off, int nb) {
  __shared__ int s[1024];
  int t = threadIdx.x;
  int v = (t < nb) ? blk[t] : 0;
  s[t] = v;
  __syncthreads();
  for (int off = 1; off < 1024; off <<= 1) {
    int u = (t >= off) ? s[t - off] : 0;
    __syncthreads();
    s[t] += u;
    __syncthreads();
  }
  if (t < nb) blk_off[t] = s[t] - v;  // exclusive
}

__global__ __launch_bounds__(256) void scan_out_kernel(const int* __restrict__ deg,
                                                       const int* __restrict__ blk_off,
                                                       int* __restrict__ out, int n) {
  int t = threadIdx.x;
  int lane = t & 63;
  int w = t >> 6;
  int i = blockIdx.x * 256 + t;
  int v = (i < n) ? deg[i] : 0;
  int inc = v;
#pragma unroll
  for (int off = 1; off < 64; off <<= 1) {
    int u = __shfl_up(inc, off);
    if (lane >= off) inc += u;
  }
  __shared__ int wsum[4];
  if (lane == 63) wsum[w] = inc;
  __syncthreads();
  int woff = 0;
  for (int k = 0; k < w; ++k) woff += wsum[k];
  int ex = blk_off[blockIdx.x] + woff + inc - v;
  if (i < n) out[i] = ex;
  if (i == n - 1) out[n] = ex + v;
}

__global__ __launch_bounds__(256) void scatter_rec_kernel(const int* __restrict__ ei,
                                                          const int* __restrict__ off_arr,
                                                          int* __restrict__ rec, int E, int N,
                                                          int B, int chunk) {
  __shared__ int cur[256];
  int w = blockIdx.x;
  int t = threadIdx.x;
  for (int b = t; b < B; b += 256) cur[b] = off_arr[b * WSC + w];
  __syncthreads();
  int beg = w * chunk, end = min(beg + chunk, E + N);
  for (int i = beg + t; i < end; i += 256) {
    int s, d;
    if (i < E) { s = ei[i]; d = ei[E + i]; } else { s = d = i - E; }
    int pos = atomicAdd(&cur[d >> BSH], 1);
    rec[pos] = s | ((d & (BNODES - 1)) << 20);
  }
}

__global__ __launch_bounds__(512) void csr_build_kernel(const int* __restrict__ rec,
                                                        const int* __restrict__ off_arr,
                                                        int* __restrict__ row_ptr,
                                                        int* __restrict__ csr, int N, int B,
                                                        int n) {
  __shared__ int deg[BNODES];
  __shared__ int scn[BNODES];
  __shared__ int cur[BNODES];
  int b = blockIdx.x;
  int t = threadIdx.x;
  int bs = b << BSH;
  int nn = min(BNODES, N - bs);
  int base = off_arr[b * WSC];
  int rend = (b == B - 1) ? off_arr[n] : off_arr[(b + 1) * WSC];
  int cnt = rend - base;
  deg[t] = 0;
  __syncthreads();
  for (int i = t; i < cnt; i += 512) atomicAdd(&deg[rec[base + i] >> 20], 1);
  __syncthreads();
  int v = deg[t];
  scn[t] = v;
  __syncthreads();
  for (int off = 1; off < 512; off <<= 1) {
    int u = (t >= off) ? scn[t - off] : 0;
    __syncthreads();
    scn[t] += u;
    __syncthreads();
  }
  int excl = scn[t] - v;
  if (t < nn) row_ptr[bs + t] = base + excl;
  cur[t] = base + excl;
  __syncthreads();
  for (int i = t; i < cnt; i += 512) {
    int r = rec[base + i];
    int pos = atomicAdd(&cur[r >> 20], 1);
    csr[pos] = r & 0xFFFFF;
  }
  if (b == B - 1 && t == 0) row_ptr[N] = base + cnt;
}

// ---------------- MFMA projection ----------------
// Wave = 16-row tile. C layout: col=lane&15, row=(lane>>4)*4+reg.
// Tile 4 cols 64/65 = s_src/s_dst.

__global__ __launch_bounds__(256) void mfma_project_kernel(
    const unsigned short* __restrict__ xb, const unsigned short* __restrict__ wext,
    unsigned short* __restrict__ h_bf, float* __restrict__ s_src, float* __restrict__ s_dst,
    int N) {
  int lane = threadIdx.x & 63;
  int c = lane & 15, g = lane >> 4;
  int wv = (blockIdx.x * blockDim.x + threadIdx.x) >> 6;
  int nw = (gridDim.x * blockDim.x) >> 6;
  bf16x8 bf[5][2];
#pragma unroll
  for (int t = 0; t < 5; ++t)
#pragma unroll
    for (int kb = 0; kb < 2; ++kb) {
      bf16x8 tmp;
#pragma unroll
      for (int j = 0; j < 8; ++j)
        tmp[j] = (short)wext[(size_t)(kb * 32 + g * 8 + j) * WCOL + t * 16 + c];
      bf[t][kb] = tmp;
    }
  int ntile = N >> 4;
  for (int tile = wv; tile < ntile; tile += nw) {
    int r0 = tile << 4;
    bf16x8 a0 = *(const bf16x8*)(xb + (size_t)(r0 + c) * D + g * 8);
    bf16x8 a1 = *(const bf16x8*)(xb + (size_t)(r0 + c) * D + 32 + g * 8);
    f32x4 acc[5] = {};
#pragma unroll
    for (int t = 0; t < 5; ++t) {
      acc[t] = __builtin_amdgcn_mfma_f32_16x16x32_bf16(a0, bf[t][0], acc[t], 0, 0, 0);
      acc[t] = __builtin_amdgcn_mfma_f32_16x16x32_bf16(a1, bf[t][1], acc[t], 0, 0, 0);
    }
#pragma unroll
    for (int t = 0; t < 4; ++t)
#pragma unroll
      for (int r = 0; r < 4; ++r)
        h_bf[(size_t)(r0 + g * 4 + r) * D + t * 16 + c] = f2bf(acc[t][r]);
    if (c == 0) {
#pragma unroll
      for (int r = 0; r < 4; ++r) s_src[r0 + g * 4 + r] = acc[4][r];
    }
    if (c == 1) {
#pragma unroll
      for (int r = 0; r < 4; ++r) s_dst[r0 + g * 4 + r] = acc[4][r];
    }
  }
}

// final projection: out = xb @ Wout + bout (f32 out)
__global__ __launch_bounds__(256) void mfma_out_kernel(
    const unsigned short* __restrict__ xb, const unsigned short* __restrict__ wext,
    const float* __restrict__ bout, float* __restrict__ out, int N) {
  int lane = threadIdx.x & 63;
  int c = lane & 15, g = lane >> 4;
  int wv = (blockIdx.x * blockDim.x + threadIdx.x) >> 6;
  int nw = (gridDim.x * blockDim.x) >> 6;
  bf16x8 bf[4][2];
#pragma unroll
  for (int t = 0; t < 4; ++t)
#pragma unroll
    for (int kb = 0; kb < 2; ++kb) {
      bf16x8 tmp;
#pragma unroll
      for (int j = 0; j < 8; ++j)
        tmp[j] = (short)wext[(size_t)(kb * 32 + g * 8 + j) * WCOL + t * 16 + c];
      bf[t][kb] = tmp;
    }
  float bv[4];
#pragma unroll
  for (int t = 0; t < 4; ++t) bv[t] = bout[t * 16 + c];
  int ntile = N >> 4;
  for (int tile = wv; tile < ntile; tile += nw) {
    int r0 = tile << 4;
    bf16x8 a0 = *(const bf16x8*)(xb + (size_t)(r0 + c) * D + g * 8);
    bf16x8 a1 = *(const bf16x8*)(xb + (size_t)(r0 + c) * D + 32 + g * 8);
    f32x4 acc[4] = {};
#pragma unroll
    for (int t = 0; t < 4; ++t) {
      acc[t] = __builtin_amdgcn_mfma_f32_16x16x32_bf16(a0, bf[t][0], acc[t], 0, 0, 0);
      acc[t] = __builtin_amdgcn_mfma_f32_16x16x32_bf16(a1, bf[t][1], acc[t], 0, 0, 0);
    }
#pragma unroll
    for (int t = 0; t < 4; ++t)
#pragma unroll
      for (int r = 0; r < 4; ++r)
        out[(size_t)(r0 + g * 4 + r) * D + t * 16 + c] = acc[t][r] + bv[t];
  }
}

// ---------------- fused attention: online softmax + weighted aggregation ----------------
// 4 nodes per wave, 16 lanes per node (lane l owns features 4l..4l+3).
// Full 16-edge chunks run mask-free; remainder loop is exact-count.
// Rescale only when the running max grows. Output bf16 only.

__global__ __launch_bounds__(256) void aggregate_kernel(
    const unsigned short* __restrict__ h_bf, const float* __restrict__ s_src,
    const float* __restrict__ s_dst, const int* __restrict__ row_ptr,
    const int* __restrict__ csr, const float* __restrict__ bias,
    unsigned short* __restrict__ xab, int N) {
  int lane = threadIdx.x & 63;
  int l = lane & 15;
  int gbase = lane & 48;
  int wid = (blockIdx.x * blockDim.x + threadIdx.x) >> 6;
  int node = wid * 4 + (lane >> 4);
  if (node >= N) return;
  int beg = row_ptr[node], end = row_ptr[node + 1];
  float sd = s_dst[node];
  const ushort4* hb4 = (const ushort4*)h_bf;
  float4 bv = ((const float4*)bias)[l];

  float m = -3.4e38f;
  float denom = 0.f;
  float4 acc = {0.f, 0.f, 0.f, 0.f};
  int base = beg;
  // full chunks: no validity masks
  for (; base + 16 <= end; base += 16) {
    int s = csr[base + l];
    float e = lrelu(s_src[s] + sd, 0.2f);
    float mc = e;
#pragma unroll
    for (int off = 8; off; off >>= 1) mc = fmaxf(mc, __shfl_xor(mc, off));
    if (mc > m) {
      float sc = __expf(m - mc);
      denom *= sc;
      acc.x *= sc; acc.y *= sc; acc.z *= sc; acc.w *= sc;
      m = mc;
    }
    float p = __expf(e - m);
    float ps = p;
#pragma unroll
    for (int off = 8; off; off >>= 1) ps += __shfl_xor(ps, off);
    denom += ps;
#pragma unroll
    for (int k = 0; k < 16; ++k) {
      float pk = __shfl(p, gbase | k);
      int sk = __shfl(s, gbase | k);
      ushort4 hb = hb4[(size_t)sk * 16 + l];
      acc.x = fmaf(pk, bf2f(hb.x), acc.x);
      acc.y = fmaf(pk, bf2f(hb.y), acc.y);
      acc.z = fmaf(pk, bf2f(hb.z), acc.z);
      acc.w = fmaf(pk, bf2f(hb.w), acc.w);
    }
  }
  int rem = end - base;
  if (rem) {
    bool valid = l < rem;
    int s = valid ? csr[base + l] : 0;
    float e = valid ? lrelu(s_src[s] + sd, 0.2f) : -3.4e38f;
    float mc = e;
#pragma unroll
    for (int off = 8; off; off >>= 1) mc = fmaxf(mc, __shfl_xor(mc, off));
    if (mc > m) {
      float sc = __expf(m - mc);
      denom *= sc;
      acc.x *= sc; acc.y *= sc; acc.z *= sc; acc.w *= sc;
      m = mc;
    }
    float p = valid ? __expf(e - m) : 0.f;
    float ps = p;
#pragma unroll
    for (int off = 8; off; off >>= 1) ps += __shfl_xor(ps, off);
    denom += ps;
    for (int k = 0; k < rem; ++k) {
      float pk = __shfl(p, gbase | k);
      int sk = __shfl(s, gbase | k);
      ushort4 hb = hb4[(size_t)sk * 16 + l];
      acc.x = fmaf(pk, bf2f(hb.x), acc.x);
      acc.y = fmaf(pk, bf2f(hb.y), acc.y);
      acc.z = fmaf(pk, bf2f(hb.z), acc.z);
      acc.w = fmaf(pk, bf2f(hb.w), acc.w);
    }
  }
  float inv = 1.f / (denom + 1e-16f);
  float4 o;
  o.x = lrelu(fmaf(acc.x, inv, bv.x), 0.01f);
  o.y = lrelu(fmaf(acc.y, inv, bv.y), 0.01f);
  o.z = lrelu(fmaf(acc.z, inv, bv.z), 0.01f);
  o.w = lrelu(fmaf(acc.w, inv, bv.w), 0.01f);
  ushort4 ob = {f2bf(o.x), f2bf(o.y), f2bf(o.z), f2bf(o.w)};
  ((ushort4*)xab)[(size_t)node * 16 + l] = ob;
}

// ---------------- virtual node ----------------
// pool reads bf16 node features (1 ushort/lane = coalesced 128B rows).

__global__ __launch_bounds__(256) void pool_kernel(
    const unsigned short* __restrict__ xab, const int* __restrict__ batch, int N,
    float* __restrict__ pooled) {
  int lane = threadIdx.x & 63;
  int wid = (blockIdx.x * blockDim.x + threadIdx.x) >> 6;
  int nw = (gridDim.x * blockDim.x) >> 6;
  int chunk = (N + nw - 1) / nw;
  int beg = wid * chunk;
  int end = min(beg + chunk, N);
  if (beg >= end) return;
  int cur = batch[beg];
  float acc = 0.f;
  for (int r = beg; r < end; ++r) {
    int g = batch[r];
    if (g != cur) {
      atomicAdd(&pooled[(size_t)cur * D + lane], acc);
      acc = 0.f;
      cur = g;
    }
    acc += bf2f(xab[(size_t)r * D + lane]);
  }
  atomicAdd(&pooled[(size_t)cur * D + lane], acc);
}

__device__ __forceinline__ float mlp64(float v, const float* __restrict__ W,
                                       const float* __restrict__ b, int lane) {
  float u = b[lane];
#pragma unroll
  for (int k = 0; k < D; ++k) u = fmaf(__shfl(v, k), W[k * D + lane], u);
  return fmaxf(u, 0.f);
}

__global__ __launch_bounds__(64) void vn_mlp_kernel(
    const float* __restrict__ pooled, const float* __restrict__ vn_emb,
    const float* __restrict__ Wm1, const float* __restrict__ bm1,
    const float* __restrict__ Wm2, const float* __restrict__ bm2,
    const float* __restrict__ Wf1, const float* __restrict__ bf1,
    const float* __restrict__ Wf2, const float* __restrict__ bf2,
    float* __restrict__ out) {
  int g = blockIdx.x;
  int lane = threadIdx.x;
  float v = pooled[(size_t)g * D + lane] + vn_emb[lane];
  v = mlp64(v, Wm1, bm1, lane);
  v = mlp64(v, Wm2, bm2, lane);
  v = mlp64(v, Wf1, bf1, lane);
  v = mlp64(v, Wf2, bf2, lane);
  out[(size_t)g * D + lane] = v;
}

// ---------------- launch ----------------

extern "C" void kernel_launch(void* const* d_in, const int* in_sizes, int n_in,
                              void* d_out, int out_size, void* d_ws, size_t ws_size,
                              hipStream_t stream) {
  const float* x = (const float*)d_in[0];
  const int* ei = (const int*)d_in[1];
  const int* batch = (const int*)d_in[2];
  const int N = in_sizes[0] / D;
  const int E = in_sizes[1] / 2;
  const int G = 64;

  const float* W[3] = {(const float*)d_in[4], (const float*)d_in[8], (const float*)d_in[12]};
  const float* asrc[3] = {(const float*)d_in[5], (const float*)d_in[9], (const float*)d_in[13]};
  const float* adst[3] = {(const float*)d_in[6], (const float*)d_in[10], (const float*)d_in[14]};
  const float* bias[3] = {(const float*)d_in[7], (const float*)d_in[11], (const float*)d_in[15]};
  const float* Wout = (const float*)d_in[16];
  const float* bout = (const float*)d_in[17];
  const float* vn_emb = (const float*)d_in[18];
  const float* Wm1 = (const float*)d_in[19];
  const float* bm1 = (const float*)d_in[20];
  const float* Wm2 = (const float*)d_in[21];
  const float* bm2 = (const float*)d_in[22];
  const float* Wf1 = (const float*)d_in[23];
  const float* bf1 = (const float*)d_in[24];
  const float* Wf2 = (const float*)d_in[25];
  const float* bf2 = (const float*)d_in[26];

  const int ET = E + N;
  const int B = (N + BNODES - 1) >> BSH;  // 196 buckets
  const int n = B * WSC;                  // count/offset array length
  const int nb2 = (n + 255) / 256;        // <= 1024
  const int chunk = (ET + WSC - 1) / WSC;

  // workspace carve
  unsigned short* h_bf = (unsigned short*)d_ws;        // N*64 bf16
  unsigned short* xab = h_bf + (size_t)N * D;          // N*64 bf16 (layer-input)
  float* s_src = (float*)(xab + (size_t)N * D);        // N
  float* s_dst = s_src + N;                            // N
  int* row_ptr = (int*)(s_dst + N);                    // N+1
  int* csr = row_ptr + N + 1;                          // ET
  int* rec = csr + ET;                                 // ET
  int* cnt = rec + ET;                                 // n
  int* off_arr = cnt + n;                              // n+1
  int* blk = off_arr + n + 1;                          // nb2
  int* blk_off = blk + 1024;                           // nb2
  float* pooled = (float*)(blk_off + 1024);            // G*D
  unsigned short* wext = (unsigned short*)(pooled + (size_t)G * D);  // 4*64*80

  hipMemsetAsync(pooled, 0, (size_t)G * D * sizeof(float), stream);
  convert_kernel<<<((N * D / 4) + 255) / 256, 256, 0, stream>>>(x, xab, (size_t)N * D / 4);
  prep_kernel<<<4, 64, 0, stream>>>(W[0], asrc[0], adst[0], W[1], asrc[1], adst[1],
                                    W[2], asrc[2], adst[2], Wout, wext);
  count_kernel<<<WSC, 256, 0, stream>>>(ei, cnt, E, N, B, chunk);
  block_sum_kernel<<<nb2, 256, 0, stream>>>(cnt, blk, n);
  blk_scan_kernel<<<1, 1024, 0, stream>>>(blk, blk_off, nb2);
  scan_out_kernel<<<nb2, 256, 0, stream>>>(cnt, blk_off, off_arr, n);
  scatter_rec_kernel<<<WSC, 256, 0, stream>>>(ei, off_arr, rec, E, N, B, chunk);
  csr_build_kernel<<<B, 512, 0, stream>>>(rec, off_arr, row_ptr, csr, N, B, n);

  for (int l = 0; l < 3; ++l) {
    mfma_project_kernel<<<512, 256, 0, stream>>>(
        xab, wext + (size_t)l * D * WCOL, h_bf, s_src, s_dst, N);
    aggregate_kernel<<<(N + 15) / 16, 256, 0, stream>>>(
        h_bf, s_src, s_dst, row_ptr, csr, bias[l], xab, N);
  }

  mfma_out_kernel<<<512, 256, 0, stream>>>(xab, wext + (size_t)3 * D * WCOL, bout,
                                           (float*)d_out, N);
  pool_kernel<<<512, 256, 0, stream>>>(xab, batch, N, pooled);
  vn_mlp_kernel<<<G, 64, 0, stream>>>(pooled, vn_emb, Wm1, bm1, Wm2, bm2, Wf1, bf1, Wf2, bf2,
                                      (float*)d_out + (size_t)N * D);
}

// Round 11
// 368.785 us; speedup vs baseline: 1.1309x; 1.1309x over previous
//
#include <hip/hip_runtime.h>

// GAT (3 layers, heads=1) + virtual-node MLP on MI355X.
// CSR via atomic-free counting sort; projections via MFMA bf16 GEMM
// (attention dots fused as 2 extra B columns); fused online-softmax aggregate
// (CHUNK=32 single-chain, branchless masked slots, bf16 node features).

constexpr int D = 64;
constexpr int BSH = 9;            // log2(nodes per bucket)
constexpr int BNODES = 1 << BSH;  // 512 nodes per bucket
constexpr int WSC = 512;          // scatter workgroups
constexpr int WCOL = 80;          // Wext padded cols (64 + s_src + s_dst + pad)

typedef __attribute__((ext_vector_type(8))) short bf16x8;
typedef __attribute__((ext_vector_type(4))) float f32x4;

__device__ __forceinline__ float lrelu(float v, float s) { return v >= 0.f ? v : v * s; }

__device__ __forceinline__ unsigned short f2bf(float f) {
  unsigned u = __float_as_uint(f);
  return (unsigned short)((u + 0x7FFFu + ((u >> 16) & 1u)) >> 16);
}
__device__ __forceinline__ float bf2f(unsigned short b) {
  return __uint_as_float((unsigned)b << 16);
}

// ---------------- f32 -> bf16 bulk convert ----------------

__global__ __launch_bounds__(256) void convert_kernel(const float* __restrict__ in,
                                                      unsigned short* __restrict__ out,
                                                      size_t n4) {
  size_t i = (size_t)blockIdx.x * blockDim.x + threadIdx.x;
  if (i >= n4) return;
  float4 v = ((const float4*)in)[i];
  ushort4 o = {f2bf(v.x), f2bf(v.y), f2bf(v.z), f2bf(v.w)};
  ((ushort4*)out)[i] = o;
}

// ---------------- Wext build: [W | W.a_src | W.a_dst | 0] as bf16 [64][80] ----------------

__global__ __launch_bounds__(64) void prep_kernel(
    const float* __restrict__ W0, const float* __restrict__ as0, const float* __restrict__ ad0,
    const float* __restrict__ W1, const float* __restrict__ as1, const float* __restrict__ ad1,
    const float* __restrict__ W2, const float* __restrict__ as2, const float* __restrict__ ad2,
    const float* __restrict__ W3, unsigned short* __restrict__ wext) {
  int b = blockIdx.x;
  int k = threadIdx.x;
  const float* W = b == 0 ? W0 : b == 1 ? W1 : b == 2 ? W2 : W3;
  const float* as = b == 0 ? as0 : b == 1 ? as1 : as2;
  const float* ad = b == 0 ? ad0 : b == 1 ? ad1 : ad2;
  unsigned short* o = wext + (size_t)b * D * WCOL + (size_t)k * WCOL;
  float ss = 0.f, sd = 0.f;
  for (int c = 0; c < D; ++c) {
    float w = W[k * D + c];
    o[c] = f2bf(w);
    if (b < 3) { ss += w * as[c]; sd += w * ad[c]; }
  }
  o[64] = (b < 3) ? f2bf(ss) : 0;
  o[65] = (b < 3) ? f2bf(sd) : 0;
  for (int c = 66; c < WCOL; ++c) o[c] = 0;
}

// ---------------- CSR build (atomic-free counting sort) ----------------

__global__ __launch_bounds__(256) void count_kernel(const int* __restrict__ ei,
                                                    int* __restrict__ cnt, int E, int N,
                                                    int B, int chunk) {
  __shared__ int hist[256];
  int w = blockIdx.x;
  int t = threadIdx.x;
  for (int b = t; b < B; b += 256) hist[b] = 0;
  __syncthreads();
  int beg = w * chunk, end = min(beg + chunk, E + N);
  for (int i = beg + t; i < end; i += 256) {
    int d = (i < E) ? ei[E + i] : (i - E);
    atomicAdd(&hist[d >> BSH], 1);
  }
  __syncthreads();
  for (int b = t; b < B; b += 256) cnt[b * WSC + w] = hist[b];
}

__global__ __launch_bounds__(256) void block_sum_kernel(const int* __restrict__ deg,
                                                        int* __restrict__ blk, int n) {
  int t = threadIdx.x;
  int i = blockIdx.x * 256 + t;
  int v = (i < n) ? deg[i] : 0;
#pragma unroll
  for (int off = 32; off; off >>= 1) v += __shfl_xor(v, off);
  __shared__ int ws[4];
  if ((t & 63) == 0) ws[t >> 6] = v;
  __syncthreads();
  if (t == 0) blk[blockIdx.x] = ws[0] + ws[1] + ws[2] + ws[3];
}

__global__ __launch_bounds__(1024) void blk_scan_kernel(int* __restrict__ blk,
                                                        int* __restrict__ blk_off, int nb) {
  __shared__ int s[1024];
  int t = threadIdx.x;
  int v = (t < nb) ? blk[t] : 0;
  s[t] = v;
  __syncthreads();
  for (int off = 1; off < 1024; off <<= 1) {
    int u = (t >= off) ? s[t - off] : 0;
    __syncthreads();
    s[t] += u;
    __syncthreads();
  }
  if (t < nb) blk_off[t] = s[t] - v;  // exclusive
}

__global__ __launch_bounds__(256) void scan_out_kernel(const int* __restrict__ deg,
                                                       const int* __restrict__ blk_off,
                                                       int* __restrict__ out, int n) {
  int t = threadIdx.x;
  int lane = t & 63;
  int w = t >> 6;
  int i = blockIdx.x * 256 + t;
  int v = (i < n) ? deg[i] : 0;
  int inc = v;
#pragma unroll
  for (int off = 1; off < 64; off <<= 1) {
    int u = __shfl_up(inc, off);
    if (lane >= off) inc += u;
  }
  __shared__ int wsum[4];
  if (lane == 63) wsum[w] = inc;
  __syncthreads();
  int woff = 0;
  for (int k = 0; k < w; ++k) woff += wsum[k];
  int ex = blk_off[blockIdx.x] + woff + inc - v;
  if (i < n) out[i] = ex;
  if (i == n - 1) out[n] = ex + v;
}

__global__ __launch_bounds__(256) void scatter_rec_kernel(const int* __restrict__ ei,
                                                          const int* __restrict__ off_arr,
                                                          int* __restrict__ rec, int E, int N,
                                                          int B, int chunk) {
  __shared__ int cur[256];
  int w = blockIdx.x;
  int t = threadIdx.x;
  for (int b = t; b < B; b += 256) cur[b] = off_arr[b * WSC + w];
  __syncthreads();
  int beg = w * chunk, end = min(beg + chunk, E + N);
  for (int i = beg + t; i < end; i += 256) {
    int s, d;
    if (i < E) { s = ei[i]; d = ei[E + i]; } else { s = d = i - E; }
    int pos = atomicAdd(&cur[d >> BSH], 1);
    rec[pos] = s | ((d & (BNODES - 1)) << 20);
  }
}

__global__ __launch_bounds__(512) void csr_build_kernel(const int* __restrict__ rec,
                                                        const int* __restrict__ off_arr,
                                                        int* __restrict__ row_ptr,
                                                        int* __restrict__ csr, int N, int B,
                                                        int n) {
  __shared__ int deg[BNODES];
  __shared__ int scn[BNODES];
  __shared__ int cur[BNODES];
  int b = blockIdx.x;
  int t = threadIdx.x;
  int bs = b << BSH;
  int nn = min(BNODES, N - bs);
  int base = off_arr[b * WSC];
  int rend = (b == B - 1) ? off_arr[n] : off_arr[(b + 1) * WSC];
  int cnt = rend - base;
  deg[t] = 0;
  __syncthreads();
  for (int i = t; i < cnt; i += 512) atomicAdd(&deg[rec[base + i] >> 20], 1);
  __syncthreads();
  int v = deg[t];
  scn[t] = v;
  __syncthreads();
  for (int off = 1; off < 512; off <<= 1) {
    int u = (t >= off) ? scn[t - off] : 0;
    __syncthreads();
    scn[t] += u;
    __syncthreads();
  }
  int excl = scn[t] - v;
  if (t < nn) row_ptr[bs + t] = base + excl;
  cur[t] = base + excl;
  __syncthreads();
  for (int i = t; i < cnt; i += 512) {
    int r = rec[base + i];
    int pos = atomicAdd(&cur[r >> 20], 1);
    csr[pos] = r & 0xFFFFF;
  }
  if (b == B - 1 && t == 0) row_ptr[N] = base + cnt;
}

// ---------------- MFMA projection ----------------
// Wave = 16-row tile. C layout: col=lane&15, row=(lane>>4)*4+reg.
// Tile 4 cols 64/65 = s_src/s_dst.

__global__ __launch_bounds__(256) void mfma_project_kernel(
    const unsigned short* __restrict__ xb, const unsigned short* __restrict__ wext,
    unsigned short* __restrict__ h_bf, float* __restrict__ s_src, float* __restrict__ s_dst,
    int N) {
  int lane = threadIdx.x & 63;
  int c = lane & 15, g = lane >> 4;
  int wv = (blockIdx.x * blockDim.x + threadIdx.x) >> 6;
  int nw = (gridDim.x * blockDim.x) >> 6;
  bf16x8 bf[5][2];
#pragma unroll
  for (int t = 0; t < 5; ++t)
#pragma unroll
    for (int kb = 0; kb < 2; ++kb) {
      bf16x8 tmp;
#pragma unroll
      for (int j = 0; j < 8; ++j)
        tmp[j] = (short)wext[(size_t)(kb * 32 + g * 8 + j) * WCOL + t * 16 + c];
      bf[t][kb] = tmp;
    }
  int ntile = N >> 4;
  for (int tile = wv; tile < ntile; tile += nw) {
    int r0 = tile << 4;
    bf16x8 a0 = *(const bf16x8*)(xb + (size_t)(r0 + c) * D + g * 8);
    bf16x8 a1 = *(const bf16x8*)(xb + (size_t)(r0 + c) * D + 32 + g * 8);
    f32x4 acc[5] = {};
#pragma unroll
    for (int t = 0; t < 5; ++t) {
      acc[t] = __builtin_amdgcn_mfma_f32_16x16x32_bf16(a0, bf[t][0], acc[t], 0, 0, 0);
      acc[t] = __builtin_amdgcn_mfma_f32_16x16x32_bf16(a1, bf[t][1], acc[t], 0, 0, 0);
    }
#pragma unroll
    for (int t = 0; t < 4; ++t)
#pragma unroll
      for (int r = 0; r < 4; ++r)
        h_bf[(size_t)(r0 + g * 4 + r) * D + t * 16 + c] = f2bf(acc[t][r]);
    if (c == 0) {
#pragma unroll
      for (int r = 0; r < 4; ++r) s_src[r0 + g * 4 + r] = acc[4][r];
    }
    if (c == 1) {
#pragma unroll
      for (int r = 0; r < 4; ++r) s_dst[r0 + g * 4 + r] = acc[4][r];
    }
  }
}

// final projection: out = xb @ Wout + bout (f32 out)
__global__ __launch_bounds__(256) void mfma_out_kernel(
    const unsigned short* __restrict__ xb, const unsigned short* __restrict__ wext,
    const float* __restrict__ bout, float* __restrict__ out, int N) {
  int lane = threadIdx.x & 63;
  int c = lane & 15, g = lane >> 4;
  int wv = (blockIdx.x * blockDim.x + threadIdx.x) >> 6;
  int nw = (gridDim.x * blockDim.x) >> 6;
  bf16x8 bf[4][2];
#pragma unroll
  for (int t = 0; t < 4; ++t)
#pragma unroll
    for (int kb = 0; kb < 2; ++kb) {
      bf16x8 tmp;
#pragma unroll
      for (int j = 0; j < 8; ++j)
        tmp[j] = (short)wext[(size_t)(kb * 32 + g * 8 + j) * WCOL + t * 16 + c];
      bf[t][kb] = tmp;
    }
  float bv[4];
#pragma unroll
  for (int t = 0; t < 4; ++t) bv[t] = bout[t * 16 + c];
  int ntile = N >> 4;
  for (int tile = wv; tile < ntile; tile += nw) {
    int r0 = tile << 4;
    bf16x8 a0 = *(const bf16x8*)(xb + (size_t)(r0 + c) * D + g * 8);
    bf16x8 a1 = *(const bf16x8*)(xb + (size_t)(r0 + c) * D + 32 + g * 8);
    f32x4 acc[4] = {};
#pragma unroll
    for (int t = 0; t < 4; ++t) {
      acc[t] = __builtin_amdgcn_mfma_f32_16x16x32_bf16(a0, bf[t][0], acc[t], 0, 0, 0);
      acc[t] = __builtin_amdgcn_mfma_f32_16x16x32_bf16(a1, bf[t][1], acc[t], 0, 0, 0);
    }
#pragma unroll
    for (int t = 0; t < 4; ++t)
#pragma unroll
      for (int r = 0; r < 4; ++r)
        out[(size_t)(r0 + g * 4 + r) * D + t * 16 + c] = acc[t][r] + bv[t];
  }
}

// ---------------- fused attention: online softmax + weighted aggregation ----------------
// 4 nodes per wave, 16 lanes per node (lane l owns features 4l..4l+3).
// CHUNK=32: lane l owns edge slots l and l+16 -> one softmax chain covers
// deg<=32 (~99.9% of nodes). Branchless masked slots (invalid -> p=0, row-0
// gather is L1-hot). Output bf16 only.

__global__ __launch_bounds__(256) void aggregate_kernel(
    const unsigned short* __restrict__ h_bf, const float* __restrict__ s_src,
    const float* __restrict__ s_dst, const int* __restrict__ row_ptr,
    const int* __restrict__ csr, const float* __restrict__ bias,
    unsigned short* __restrict__ xab, int N) {
  int lane = threadIdx.x & 63;
  int l = lane & 15;
  int gbase = lane & 48;
  int wid = (blockIdx.x * blockDim.x + threadIdx.x) >> 6;
  int node = wid * 4 + (lane >> 4);
  if (node >= N) return;
  int beg = row_ptr[node], end = row_ptr[node + 1];
  float sd = s_dst[node];
  const ushort4* hb4 = (const ushort4*)h_bf;
  float4 bv = ((const float4*)bias)[l];

  float m = -3.4e38f;
  float denom = 0.f;
  float4 acc = {0.f, 0.f, 0.f, 0.f};
  for (int base = beg; base < end; base += 32) {
    int i0 = base + l, i1 = base + 16 + l;
    bool v0 = i0 < end, v1 = i1 < end;
    int s0 = v0 ? csr[i0] : 0;
    int s1 = v1 ? csr[i1] : 0;
    float e0 = v0 ? lrelu(s_src[s0] + sd, 0.2f) : -3.4e38f;
    float e1 = v1 ? lrelu(s_src[s1] + sd, 0.2f) : -3.4e38f;
    float mc = fmaxf(e0, e1);
#pragma unroll
    for (int off = 8; off; off >>= 1) mc = fmaxf(mc, __shfl_xor(mc, off));
    float mn = fmaxf(m, mc);
    float scale = __expf(m - mn);  // first chunk: exp(-inf)=0
    float p0 = v0 ? __expf(e0 - mn) : 0.f;
    float p1 = v1 ? __expf(e1 - mn) : 0.f;
    float ps = p0 + p1;
#pragma unroll
    for (int off = 8; off; off >>= 1) ps += __shfl_xor(ps, off);
    denom = denom * scale + ps;
    acc.x *= scale; acc.y *= scale; acc.z *= scale; acc.w *= scale;
    m = mn;
#pragma unroll
    for (int k = 0; k < 16; ++k) {
      float pk0 = __shfl(p0, gbase | k);
      int sk0 = __shfl(s0, gbase | k);
      float pk1 = __shfl(p1, gbase | k);
      int sk1 = __shfl(s1, gbase | k);
      ushort4 hb0 = hb4[(size_t)sk0 * 16 + l];
      ushort4 hb1 = hb4[(size_t)sk1 * 16 + l];
      acc.x = fmaf(pk0, bf2f(hb0.x), acc.x);
      acc.y = fmaf(pk0, bf2f(hb0.y), acc.y);
      acc.z = fmaf(pk0, bf2f(hb0.z), acc.z);
      acc.w = fmaf(pk0, bf2f(hb0.w), acc.w);
      acc.x = fmaf(pk1, bf2f(hb1.x), acc.x);
      acc.y = fmaf(pk1, bf2f(hb1.y), acc.y);
      acc.z = fmaf(pk1, bf2f(hb1.z), acc.z);
      acc.w = fmaf(pk1, bf2f(hb1.w), acc.w);
    }
  }
  float inv = 1.f / (denom + 1e-16f);
  float4 o;
  o.x = lrelu(fmaf(acc.x, inv, bv.x), 0.01f);
  o.y = lrelu(fmaf(acc.y, inv, bv.y), 0.01f);
  o.z = lrelu(fmaf(acc.z, inv, bv.z), 0.01f);
  o.w = lrelu(fmaf(acc.w, inv, bv.w), 0.01f);
  ushort4 ob = {f2bf(o.x), f2bf(o.y), f2bf(o.z), f2bf(o.w)};
  ((ushort4*)xab)[(size_t)node * 16 + l] = ob;
}

// ---------------- virtual node ----------------
// pool reads bf16 node features (1 ushort/lane = coalesced 128B rows).

__global__ __launch_bounds__(256) void pool_kernel(
    const unsigned short* __restrict__ xab, const int* __restrict__ batch, int N,
    float* __restrict__ pooled) {
  int lane = threadIdx.x & 63;
  int wid = (blockIdx.x * blockDim.x + threadIdx.x) >> 6;
  int nw = (gridDim.x * blockDim.x) >> 6;
  int chunk = (N + nw - 1) / nw;
  int beg = wid * chunk;
  int end = min(beg + chunk, N);
  if (beg >= end) return;
  int cur = batch[beg];
  float acc = 0.f;
  for (int r = beg; r < end; ++r) {
    int g = batch[r];
    if (g != cur) {
      atomicAdd(&pooled[(size_t)cur * D + lane], acc);
      acc = 0.f;
      cur = g;
    }
    acc += bf2f(xab[(size_t)r * D + lane]);
  }
  atomicAdd(&pooled[(size_t)cur * D + lane], acc);
}

__device__ __forceinline__ float mlp64(float v, const float* __restrict__ W,
                                       const float* __restrict__ b, int lane) {
  float u = b[lane];
#pragma unroll
  for (int k = 0; k < D; ++k) u = fmaf(__shfl(v, k), W[k * D + lane], u);
  return fmaxf(u, 0.f);
}

__global__ __launch_bounds__(64) void vn_mlp_kernel(
    const float* __restrict__ pooled, const float* __restrict__ vn_emb,
    const float* __restrict__ Wm1, const float* __restrict__ bm1,
    const float* __restrict__ Wm2, const float* __restrict__ bm2,
    const float* __restrict__ Wf1, const float* __restrict__ bf1,
    const float* __restrict__ Wf2, const float* __restrict__ bf2,
    float* __restrict__ out) {
  int g = blockIdx.x;
  int lane = threadIdx.x;
  float v = pooled[(size_t)g * D + lane] + vn_emb[lane];
  v = mlp64(v, Wm1, bm1, lane);
  v = mlp64(v, Wm2, bm2, lane);
  v = mlp64(v, Wf1, bf1, lane);
  v = mlp64(v, Wf2, bf2, lane);
  out[(size_t)g * D + lane] = v;
}

// ---------------- launch ----------------

extern "C" void kernel_launch(void* const* d_in, const int* in_sizes, int n_in,
                              void* d_out, int out_size, void* d_ws, size_t ws_size,
                              hipStream_t stream) {
  const float* x = (const float*)d_in[0];
  const int* ei = (const int*)d_in[1];
  const int* batch = (const int*)d_in[2];
  const int N = in_sizes[0] / D;
  const int E = in_sizes[1] / 2;
  const int G = 64;

  const float* W[3] = {(const float*)d_in[4], (const float*)d_in[8], (const float*)d_in[12]};
  const float* asrc[3] = {(const float*)d_in[5], (const float*)d_in[9], (const float*)d_in[13]};
  const float* adst[3] = {(const float*)d_in[6], (const float*)d_in[10], (const float*)d_in[14]};
  const float* bias[3] = {(const float*)d_in[7], (const float*)d_in[11], (const float*)d_in[15]};
  const float* Wout = (const float*)d_in[16];
  const float* bout = (const float*)d_in[17];
  const float* vn_emb = (const float*)d_in[18];
  const float* Wm1 = (const float*)d_in[19];
  const float* bm1 = (const float*)d_in[20];
  const float* Wm2 = (const float*)d_in[21];
  const float* bm2 = (const float*)d_in[22];
  const float* Wf1 = (const float*)d_in[23];
  const float* bf1 = (const float*)d_in[24];
  const float* Wf2 = (const float*)d_in[25];
  const float* bf2 = (const float*)d_in[26];

  const int ET = E + N;
  const int B = (N + BNODES - 1) >> BSH;  // 196 buckets
  const int n = B * WSC;                  // count/offset array length
  const int nb2 = (n + 255) / 256;        // <= 1024
  const int chunk = (ET + WSC - 1) / WSC;

  // workspace carve
  unsigned short* h_bf = (unsigned short*)d_ws;        // N*64 bf16
  unsigned short* xab = h_bf + (size_t)N * D;          // N*64 bf16 (layer-input)
  float* s_src = (float*)(xab + (size_t)N * D);        // N
  float* s_dst = s_src + N;                            // N
  int* row_ptr = (int*)(s_dst + N);                    // N+1
  int* csr = row_ptr + N + 1;                          // ET
  int* rec = csr + ET;                                 // ET
  int* cnt = rec + ET;                                 // n
  int* off_arr = cnt + n;                              // n+1
  int* blk = off_arr + n + 1;                          // nb2
  int* blk_off = blk + 1024;                           // nb2
  float* pooled = (float*)(blk_off + 1024);            // G*D
  unsigned short* wext = (unsigned short*)(pooled + (size_t)G * D);  // 4*64*80

  hipMemsetAsync(pooled, 0, (size_t)G * D * sizeof(float), stream);
  convert_kernel<<<((N * D / 4) + 255) / 256, 256, 0, stream>>>(x, xab, (size_t)N * D / 4);
  prep_kernel<<<4, 64, 0, stream>>>(W[0], asrc[0], adst[0], W[1], asrc[1], adst[1],
                                    W[2], asrc[2], adst[2], Wout, wext);
  count_kernel<<<WSC, 256, 0, stream>>>(ei, cnt, E, N, B, chunk);
  block_sum_kernel<<<nb2, 256, 0, stream>>>(cnt, blk, n);
  blk_scan_kernel<<<1, 1024, 0, stream>>>(blk, blk_off, nb2);
  scan_out_kernel<<<nb2, 256, 0, stream>>>(cnt, blk_off, off_arr, n);
  scatter_rec_kernel<<<WSC, 256, 0, stream>>>(ei, off_arr, rec, E, N, B, chunk);
  csr_build_kernel<<<B, 512, 0, stream>>>(rec, off_arr, row_ptr, csr, N, B, n);

  for (int l = 0; l < 3; ++l) {
    mfma_project_kernel<<<512, 256, 0, stream>>>(
        xab, wext + (size_t)l * D * WCOL, h_bf, s_src, s_dst, N);
    aggregate_kernel<<<(N + 15) / 16, 256, 0, stream>>>(
        h_bf, s_src, s_dst, row_ptr, csr, bias[l], xab, N);
  }

  mfma_out_kernel<<<512, 256, 0, stream>>>(xab, wext + (size_t)3 * D * WCOL, bout,
                                           (float*)d_out, N);
  pool_kernel<<<512, 256, 0, stream>>>(xab, batch, N, pooled);
  vn_mlp_kernel<<<G, 64, 0, stream>>>(pooled, vn_emb, Wm1, bm1, Wm2, bm2, Wf1, bf1, Wf2, bf2,
                                      (float*)d_out + (size_t)N * D);
}